// Round 1
// 90.134 us; speedup vs baseline: 1.0505x; 1.0505x over previous
//
#include <hip/hip_runtime.h>
#include <math.h>

typedef float f2 __attribute__((ext_vector_type(2)));

// Problem constants
constexpr int NB = 64;      // batch
constexpr int NU = 2048;    // U
constexpr int ND = 1024;    // dec dim
constexpr int NE = 512;     // enc dim
constexpr int NH = 4;       // heads
constexpr int NK = 256;     // head dim
constexpr int NA = 1024;    // out dim
constexpr int NS = 16;      // U splits
constexpr int ROWS_PER_BLOCK = NU / NS;            // 128
constexpr int ROWS_PER_WAVE  = ROWS_PER_BLOCK / 4; // 32
constexpr float SCALE = 0.0625f;                   // 1/sqrt(256)

constexpr int RSPLIT = 16;
constexpr int RCH = (NH*NE)/RSPLIT;  // 128
constexpr int BT = 8;

constexpr int DSP = 16;   // D splits in k_phi (64 d each)
constexpr int KSP = 4;    // K splits in k_q   (64 k each)

// workspace layout (float offsets)
constexpr size_t WS_Q   = 0;                            // q:      131072 floats
constexpr size_t WS_CTX = WS_Q + (size_t)NB*NH*NE;      // ctxacc: 131072 floats
constexpr size_t WS_P   = WS_CTX + (size_t)NB*NH*NE;    // phi partials: 16*64*4*256 = 1M floats

// ---------------------------------------------------------------------------
// K1a: phi partials. Batched over ALL b: weights read once (was 64x re-read).
// Block (h, kc, ds): P[ds][b][h][k0+k] = sum_{d in ds-slice} dec[b][d]*phi_w[h][d][k]
// Also does replay-safe inits: zero ctxacc, zero q, bias-init out.
__global__ __launch_bounds__(256) void k_phi(
    const float* __restrict__ dec, const float* __restrict__ phi_w,
    float* __restrict__ P, float* __restrict__ q, float* __restrict__ ctxacc,
    const float* __restrict__ out_b, float* __restrict__ out)
{
  const int flat = blockIdx.x;              // 0..255
  const int kc = flat & 3;
  const int h  = (flat >> 2) & 3;
  const int ds = flat >> 4;                 // 0..15
  const int t = threadIdx.x;

  // replay-safe inits (consumed by later kernels; kernel boundary orders them)
  ctxacc[(size_t)flat*512 + t]       = 0.f;
  ctxacc[(size_t)flat*512 + 256 + t] = 0.f;
  q[(size_t)flat*512 + t]            = 0.f;
  q[(size_t)flat*512 + 256 + t]      = 0.f;
  out[(size_t)flat*256 + t] = out_b[(flat*256 + t) & (NA-1)];

  const int d0 = ds*64, k0 = kc*64;

  // stage dec[0:64][d0:d0+64] transposed -> dec_t[d][b]; pad 68 keeps
  // b128 reads 16B-aligned and spreads staging writes over 8 banks.
  __shared__ float dec_t[64][68];
  {
    const int dd = t & 63, b4 = t >> 6;
    #pragma unroll
    for (int j = 0; j < 16; ++j)
      dec_t[dd][b4*16 + j] = dec[(size_t)(b4*16 + j)*ND + d0 + dd];
  }
  __syncthreads();

  // thread owns one k (lane-coalesced phi_w stream) x 16 b's (LDS broadcast)
  const int k = t & 63, bq = t >> 6, b0 = bq*16;
  float acc[16];
  #pragma unroll
  for (int i = 0; i < 16; ++i) acc[i] = 0.f;
  const float* pw = phi_w + ((size_t)h*ND + d0)*NK + k0 + k;
  #pragma unroll 4
  for (int d = 0; d < 64; ++d) {
    float w = pw[(size_t)d*NK];
    float4 a0 = *(const float4*)&dec_t[d][b0];
    float4 a1 = *(const float4*)&dec_t[d][b0+4];
    float4 a2 = *(const float4*)&dec_t[d][b0+8];
    float4 a3 = *(const float4*)&dec_t[d][b0+12];
    acc[0]+=a0.x*w;  acc[1]+=a0.y*w;  acc[2]+=a0.z*w;  acc[3]+=a0.w*w;
    acc[4]+=a1.x*w;  acc[5]+=a1.y*w;  acc[6]+=a1.z*w;  acc[7]+=a1.w*w;
    acc[8]+=a2.x*w;  acc[9]+=a2.y*w;  acc[10]+=a2.z*w; acc[11]+=a2.w*w;
    acc[12]+=a3.x*w; acc[13]+=a3.y*w; acc[14]+=a3.z*w; acc[15]+=a3.w*w;
  }
  #pragma unroll
  for (int j = 0; j < 16; ++j)
    P[(((size_t)ds*64 + b0 + j)*NH + h)*NK + k0 + k] = acc[j];   // lanes k-consec: coalesced
}

// ---------------------------------------------------------------------------
// K1b: q[b,h,e] = sum_k (sum_ds P + phi_b) * psi_w[h,e,k], split-K over 4,
// atomically accumulated into q (zeroed by k_phi). psi_b dropped (cancels
// in softmax). Block (h, ec, ks): 64b x 64e tile over a 64-wide k slice.
__global__ __launch_bounds__(256) void k_q(
    const float* __restrict__ P, const float* __restrict__ phi_b,
    const float* __restrict__ psi_w, float* __restrict__ q)
{
  const int flat = blockIdx.x;              // 0..127
  const int ks = flat & 3;
  const int ec = (flat >> 2) & 7;
  const int h  = flat >> 5;
  const int t = threadIdx.x;
  const int k0 = ks*64, e0 = ec*64;

  __shared__ float phi_red[64][68];   // [k][b], padded for aligned b128 + banks
  __shared__ float psi_lds[64][65];   // [e][k], pad 65 -> bank (e+k)%32

  // stage psi_w[h][e0:e0+64][k0:k0+64] (rows k-consecutive: coalesced)
  {
    const int kk = t & 63, e4 = t >> 6;
    #pragma unroll
    for (int j = 0; j < 16; ++j)
      psi_lds[e4*16 + j][kk] =
          psi_w[((size_t)h*NE + e0 + e4*16 + j)*NK + k0 + kk];
  }
  // reduce D-partials (+phi_b) into phi_red[k][b]
  #pragma unroll
  for (int g = t; g < 64*64; g += 256) {
    const int b = g >> 6, kl = g & 63;   // lanes: kl consecutive -> coalesced
    float s = 0.f;
    #pragma unroll
    for (int ds = 0; ds < DSP; ++ds)
      s += P[(((size_t)ds*64 + b)*NH + h)*NK + k0 + kl];
    phi_red[kl][b] = s + phi_b[h*NK + k0 + kl];
  }
  __syncthreads();

  const int e = t & 63, bq = t >> 6, b0 = bq*16;
  float acc[16];
  #pragma unroll
  for (int i = 0; i < 16; ++i) acc[i] = 0.f;
  #pragma unroll 4
  for (int kl = 0; kl < 64; ++kl) {
    float w = psi_lds[e][kl];
    float4 a0 = *(const float4*)&phi_red[kl][b0];
    float4 a1 = *(const float4*)&phi_red[kl][b0+4];
    float4 a2 = *(const float4*)&phi_red[kl][b0+8];
    float4 a3 = *(const float4*)&phi_red[kl][b0+12];
    acc[0]+=a0.x*w;  acc[1]+=a0.y*w;  acc[2]+=a0.z*w;  acc[3]+=a0.w*w;
    acc[4]+=a1.x*w;  acc[5]+=a1.y*w;  acc[6]+=a1.z*w;  acc[7]+=a1.w*w;
    acc[8]+=a2.x*w;  acc[9]+=a2.y*w;  acc[10]+=a2.z*w; acc[11]+=a2.w*w;
    acc[12]+=a3.x*w; acc[13]+=a3.y*w; acc[14]+=a3.z*w; acc[15]+=a3.w*w;
  }
  #pragma unroll
  for (int j = 0; j < 16; ++j)
    unsafeAtomicAdd(&q[((size_t)(b0 + j)*NH + h)*NE + e0 + e], acc[j]);
}

// ---------------------------------------------------------------------------
// K2: stream enc once; energy -> exp (no max shift: |e| <~ 7; denom cancels
// in l2norm) -> ctx partial; block partials atomically summed into ctxacc.
__global__ __launch_bounds__(256, 4) void k_flash(
    const float* __restrict__ enc, const float* __restrict__ qg,
    float* __restrict__ ctxacc)
{
  const int s = blockIdx.x;
  const int b = blockIdx.y;
  const int t = threadIdx.x;
  const int wave = t >> 6;
  const int lane = t & 63;

  f2 qv[NH][4];
  const float* qb = qg + (size_t)b*NH*NE;
  #pragma unroll
  for (int h = 0; h < NH; ++h) {
    float4 a0 = *(const float4*)(qb + h*NE + 4*lane);
    float4 a1 = *(const float4*)(qb + h*NE + 256 + 4*lane);
    qv[h][0] = f2{a0.x, a0.y}; qv[h][1] = f2{a0.z, a0.w};
    qv[h][2] = f2{a1.x, a1.y}; qv[h][3] = f2{a1.z, a1.w};
  }
  f2 acc2[NH][4];
  #pragma unroll
  for (int h = 0; h < NH; ++h)
    #pragma unroll
    for (int j = 0; j < 4; ++j) acc2[h][j] = f2{0.f, 0.f};

  const int u0 = s*ROWS_PER_BLOCK + wave*ROWS_PER_WAVE;
  const float* encb = enc + ((size_t)b*NU + u0)*NE;
  #pragma unroll 2
  for (int r = 0; r < ROWS_PER_WAVE; ++r) {
    float4 v0 = *(const float4*)(encb + (size_t)r*NE + 4*lane);
    float4 v1 = *(const float4*)(encb + (size_t)r*NE + 256 + 4*lane);
    f2 e0 = f2{v0.x, v0.y}, e1 = f2{v0.z, v0.w};
    f2 e2 = f2{v1.x, v1.y}, e3 = f2{v1.z, v1.w};
    float d[NH];
    #pragma unroll
    for (int h = 0; h < NH; ++h) {
      f2 p = e0*qv[h][0] + e1*qv[h][1] + e2*qv[h][2] + e3*qv[h][3];
      d[h] = p[0] + p[1];
    }
    #pragma unroll
    for (int off = 1; off < 64; off <<= 1) {
      #pragma unroll
      for (int h = 0; h < NH; ++h) d[h] += __shfl_xor(d[h], off);
    }
    #pragma unroll
    for (int h = 0; h < NH; ++h) {
      float pf = __expf(d[h] * SCALE);
      f2 pp = f2{pf, pf};
      acc2[h][0] += pp*e0; acc2[h][1] += pp*e1;
      acc2[h][2] += pp*e2; acc2[h][3] += pp*e3;
    }
  }
  __shared__ float acc_lds[4][NH][NE];   // 32 KB
  #pragma unroll
  for (int h = 0; h < NH; ++h) {
    *(float4*)&acc_lds[wave][h][4*lane] =
        make_float4(acc2[h][0][0], acc2[h][0][1], acc2[h][1][0], acc2[h][1][1]);
    *(float4*)&acc_lds[wave][h][256 + 4*lane] =
        make_float4(acc2[h][2][0], acc2[h][2][1], acc2[h][3][0], acc2[h][3][1]);
  }
  __syncthreads();
  float* cb = ctxacc + (size_t)b*(NH*NE);
  #pragma unroll
  for (int h = 0; h < NH; ++h) {
    #pragma unroll
    for (int eo = 0; eo < 2; ++eo) {
      int e = t + eo*256;
      float v = acc_lds[0][h][e] + acc_lds[1][h][e] + acc_lds[2][h][e] + acc_lds[3][h][e];
      unsafeAtomicAdd(&cb[h*NE + e], v);
    }
  }
}

// ---------------------------------------------------------------------------
// K3: out += comb @ out_w chunk. Reads ctxacc, computes per-(b,h) l2-norm
// in-block (softmax denom cancels), split-K partials atomically added into
// bias-initialized out. grid (NA/256, NB/BT, RSPLIT).
__global__ __launch_bounds__(256) void k_out(
    const float* __restrict__ ctxacc, const float* __restrict__ out_w,
    float* __restrict__ out)
{
  const int t = threadIdx.x;
  const int a = blockIdx.x*256 + t;
  const int b0 = blockIdx.y * BT;
  const int rc = blockIdx.z;
  const int h  = rc >> 2;            // RCH=128 -> 4 chunks per head
  const int e0 = (rc & 3) * RCH;

  __shared__ float rn_lds[BT];
  const int wv = t >> 6, lane = t & 63;
  {
    const int i = 2*wv + (lane >> 5);
    const int l32 = lane & 31;
    const float* row = ctxacc + (size_t)(b0+i)*(NH*NE) + (size_t)h*NE;
    float ss = 0.f;
    #pragma unroll
    for (int j = 0; j < 16; ++j) { float v = row[l32 + 32*j]; ss += v*v; }
    #pragma unroll
    for (int off = 1; off < 32; off <<= 1) ss += __shfl_xor(ss, off);
    if (l32 == 0) rn_lds[i] = rsqrtf(fmaxf(ss, 1e-12f));
  }
  __syncthreads();

  __shared__ float c_lds[RCH][BT];   // 4 KB
  for (int g = t; g < RCH*BT; g += 256) {
    const int r = g & (RCH-1), i = g >> 7;
    c_lds[r][i] = ctxacc[(size_t)(b0+i)*(NH*NE) + (size_t)h*NE + e0 + r] * rn_lds[i];
  }
  __syncthreads();

  float accv[BT];
  #pragma unroll
  for (int i = 0; i < BT; ++i) accv[i] = 0.f;
  const float* w = out_w + ((size_t)rc*RCH)*NA + a;
  #pragma unroll 8
  for (int r = 0; r < RCH; ++r) {
    float wvv = w[(size_t)r*NA];
    float4 ca = *(const float4*)&c_lds[r][0];
    float4 cb = *(const float4*)&c_lds[r][4];
    accv[0] += ca.x*wvv; accv[1] += ca.y*wvv; accv[2] += ca.z*wvv; accv[3] += ca.w*wvv;
    accv[4] += cb.x*wvv; accv[5] += cb.y*wvv; accv[6] += cb.z*wvv; accv[7] += cb.w*wvv;
  }
  #pragma unroll
  for (int i = 0; i < BT; ++i)
    unsafeAtomicAdd(&out[(size_t)(b0+i)*NA + a], accv[i]);
}

// ---------------------------------------------------------------------------
extern "C" void kernel_launch(void* const* d_in, const int* in_sizes, int n_in,
                              void* d_out, int out_size, void* d_ws, size_t ws_size,
                              hipStream_t stream) {
  const float* dec   = (const float*)d_in[0];
  const float* enc   = (const float*)d_in[1];
  const float* phi_w = (const float*)d_in[2];
  const float* phi_b = (const float*)d_in[3];
  const float* psi_w = (const float*)d_in[4];
  // d_in[5] = psi_b: constant over u -> cancels in softmax.
  const float* out_w = (const float*)d_in[6];
  const float* out_b = (const float*)d_in[7];
  float* out = (float*)d_out;
  float* ws = (float*)d_ws;
  float* q      = ws + WS_Q;
  float* ctxacc = ws + WS_CTX;
  float* P      = ws + WS_P;

  hipLaunchKernelGGL(k_phi,   dim3(NH*4*DSP),              dim3(256), 0, stream,
                     dec, phi_w, P, q, ctxacc, out_b, out);
  hipLaunchKernelGGL(k_q,     dim3(NH*8*KSP),              dim3(256), 0, stream,
                     P, phi_b, psi_w, q);
  hipLaunchKernelGGL(k_flash, dim3(NS, NB),                dim3(256), 0, stream,
                     enc, q, ctxacc);
  hipLaunchKernelGGL(k_out,   dim3(NA/256, NB/BT, RSPLIT), dim3(256), 0, stream,
                     ctxacc, out_w, out);
}

// Round 2
// 84.706 us; speedup vs baseline: 1.1178x; 1.0641x over previous
//
#include <hip/hip_runtime.h>
#include <math.h>

typedef float f2 __attribute__((ext_vector_type(2)));

// Problem constants
constexpr int NB = 64;      // batch
constexpr int NU = 2048;    // U
constexpr int ND = 1024;    // dec dim
constexpr int NE = 512;     // enc dim
constexpr int NH = 4;       // heads
constexpr int NK = 256;     // head dim
constexpr int NA = 1024;    // out dim
constexpr int NS = 16;      // U splits
constexpr int ROWS_PER_BLOCK = NU / NS;            // 128
constexpr int ROWS_PER_WAVE  = ROWS_PER_BLOCK / 4; // 32
constexpr float SCALE = 0.0625f;                   // 1/sqrt(256)

constexpr int RSPLIT = 16;
constexpr int RCH = (NH*NE)/RSPLIT;  // 128
constexpr int BT = 8;

constexpr int DSP = 16;   // D splits in k_phi (64 d each)

// workspace layout (float offsets)
constexpr size_t WS_Q   = 0;                            // q:      131072 floats
constexpr size_t WS_CTX = WS_Q + (size_t)NB*NH*NE;      // ctxacc: 131072 floats
constexpr size_t WS_P   = WS_CTX + (size_t)NB*NH*NE;    // phi partials: 16*64*4*256 = 1M floats

// ---------------------------------------------------------------------------
// K1a: phi partials. Latency-tolerant: bulk float4 staging of phi_w slice and
// dec slice into LDS (deep independent load pipeline), compute from LDS.
// Block (h, kc, ds): P[ds][b][h][k0+k] = sum_{d in slice} dec[b][d]*phi_w[h][d][k]
// Also replay-safe inits: zero ctxacc, zero q, bias-init out.
__global__ __launch_bounds__(256) void k_phi(
    const float* __restrict__ dec, const float* __restrict__ phi_w,
    float* __restrict__ P, float* __restrict__ q, float* __restrict__ ctxacc,
    const float* __restrict__ out_b, float* __restrict__ out)
{
  const int flat = blockIdx.x;              // 0..255
  const int kc = flat & 3;
  const int h  = (flat >> 2) & 3;
  const int ds = flat >> 4;                 // 0..15
  const int t = threadIdx.x;

  // replay-safe inits (consumed by later kernels; kernel boundary orders them)
  ctxacc[(size_t)flat*512 + t]       = 0.f;
  ctxacc[(size_t)flat*512 + 256 + t] = 0.f;
  q[(size_t)flat*512 + t]            = 0.f;
  q[(size_t)flat*512 + 256 + t]      = 0.f;
  out[(size_t)flat*256 + t] = out_b[(flat*256 + t) & (NA-1)];

  const int d0 = ds*64, k0 = kc*64;

  __shared__ float phi_lds[64][64];   // 16 KB [d][k]; read lanes k-consec: 2-way free
  __shared__ float dec_t[64][68];     // 17 KB [d][b]; reads wave-uniform (broadcast)

  {
    const int kq = t & 15, r = t >> 4;        // r: 0..15
    const float* pwb = phi_w + ((size_t)h*ND + d0)*NK + k0;
    #pragma unroll
    for (int p = 0; p < 4; ++p) {             // 16 KB issued as 4 indep f4/thread
      float4 v = *(const float4*)(pwb + (size_t)(r + 16*p)*NK + 4*kq);
      *(float4*)&phi_lds[r + 16*p][4*kq] = v;
    }
    const float* db = dec + d0 + 4*kq;
    #pragma unroll
    for (int p = 0; p < 4; ++p) {             // dec[b][d-slice] -> dec_t[d][b]
      const int b = r + 16*p;
      float4 v = *(const float4*)(db + (size_t)b*ND);
      dec_t[4*kq+0][b] = v.x; dec_t[4*kq+1][b] = v.y;
      dec_t[4*kq+2][b] = v.z; dec_t[4*kq+3][b] = v.w;
    }
  }
  __syncthreads();

  // thread owns one k (lane-coalesced) x 16 b's (wave-uniform LDS broadcast)
  const int k = t & 63, bq = t >> 6, b0 = bq*16;
  f2 acc2[8];
  #pragma unroll
  for (int i = 0; i < 8; ++i) acc2[i] = f2{0.f, 0.f};
  #pragma unroll 4
  for (int d = 0; d < 64; ++d) {
    float w = phi_lds[d][k];
    f2 ww = f2{w, w};
    float4 a0 = *(const float4*)&dec_t[d][b0];
    float4 a1 = *(const float4*)&dec_t[d][b0+4];
    float4 a2 = *(const float4*)&dec_t[d][b0+8];
    float4 a3 = *(const float4*)&dec_t[d][b0+12];
    acc2[0] += f2{a0.x,a0.y}*ww; acc2[1] += f2{a0.z,a0.w}*ww;
    acc2[2] += f2{a1.x,a1.y}*ww; acc2[3] += f2{a1.z,a1.w}*ww;
    acc2[4] += f2{a2.x,a2.y}*ww; acc2[5] += f2{a2.z,a2.w}*ww;
    acc2[6] += f2{a3.x,a3.y}*ww; acc2[7] += f2{a3.z,a3.w}*ww;
  }
  float* pb = P + (((size_t)ds*64 + b0)*NH + h)*NK + k0 + k;
  #pragma unroll
  for (int j = 0; j < 8; ++j) {               // lanes k-consec: coalesced
    pb[(size_t)(2*j  )*NH*NK] = acc2[j][0];
    pb[(size_t)(2*j+1)*NH*NK] = acc2[j][1];
  }
}

// ---------------------------------------------------------------------------
// K1b: q[b,h,e] = sum_k (sum_ds P + phi_b) * psi_w[h,e,k], split-K over 4,
// atomically accumulated into q (zeroed by k_phi). psi_b dropped (cancels in
// softmax). Staging now float4-bulk (was scalar strided: latency-bound).
__global__ __launch_bounds__(256) void k_q(
    const float* __restrict__ P, const float* __restrict__ phi_b,
    const float* __restrict__ psi_w, float* __restrict__ q)
{
  const int flat = blockIdx.x;              // 0..127
  const int ks = flat & 3;
  const int ec = (flat >> 2) & 7;
  const int h  = flat >> 5;
  const int t = threadIdx.x;
  const int k0 = ks*64, e0 = ec*64;

  __shared__ float phi_red[64][68];   // [k][b]; compute reads wave-uniform
  __shared__ float psi_lds[64][65];   // [e][k]; stride 65 -> bank (e+k)%32 free

  // stage psi_w[h][e0:e0+64][k0:k0+64]: 4 indep float4 loads/thread
  {
    const int e = t >> 2, kq4 = t & 3;
    const float* pb = psi_w + ((size_t)h*NE + e0 + e)*NK + k0 + 4*kq4;
    #pragma unroll
    for (int p = 0; p < 4; ++p) {
      float4 v = *(const float4*)(pb + 16*p);
      const int kk = 4*(kq4 + 4*p);
      psi_lds[e][kk+0] = v.x; psi_lds[e][kk+1] = v.y;
      psi_lds[e][kk+2] = v.z; psi_lds[e][kk+3] = v.w;
    }
  }
  // reduce D-partials (+phi_b) into phi_red[k][b]: float4 over k, 16 indep
  // loads per chain (was 256 scalar strided loads/thread).
  {
    const int b = t >> 2, kq4 = t & 3;
    const float* pbase = P + ((size_t)b*NH + h)*NK + k0 + 4*kq4;
    #pragma unroll
    for (int p = 0; p < 4; ++p) {
      float4 s = make_float4(0.f, 0.f, 0.f, 0.f);
      #pragma unroll
      for (int dsi = 0; dsi < DSP; ++dsi) {
        float4 v = *(const float4*)(pbase + (size_t)dsi*64*NH*NK + 16*p);
        s.x += v.x; s.y += v.y; s.z += v.z; s.w += v.w;
      }
      const int kk = 4*(kq4 + 4*p);
      const float* bb = phi_b + h*NK + k0 + kk;
      phi_red[kk+0][b] = s.x + bb[0];
      phi_red[kk+1][b] = s.y + bb[1];
      phi_red[kk+2][b] = s.z + bb[2];
      phi_red[kk+3][b] = s.w + bb[3];
    }
  }
  __syncthreads();

  const int e = t & 63, bq = t >> 6, b0 = bq*16;
  f2 acc2[8];
  #pragma unroll
  for (int i = 0; i < 8; ++i) acc2[i] = f2{0.f, 0.f};
  #pragma unroll 4
  for (int kl = 0; kl < 64; ++kl) {
    float w = psi_lds[e][kl];
    f2 ww = f2{w, w};
    float4 a0 = *(const float4*)&phi_red[kl][b0];
    float4 a1 = *(const float4*)&phi_red[kl][b0+4];
    float4 a2 = *(const float4*)&phi_red[kl][b0+8];
    float4 a3 = *(const float4*)&phi_red[kl][b0+12];
    acc2[0] += f2{a0.x,a0.y}*ww; acc2[1] += f2{a0.z,a0.w}*ww;
    acc2[2] += f2{a1.x,a1.y}*ww; acc2[3] += f2{a1.z,a1.w}*ww;
    acc2[4] += f2{a2.x,a2.y}*ww; acc2[5] += f2{a2.z,a2.w}*ww;
    acc2[6] += f2{a3.x,a3.y}*ww; acc2[7] += f2{a3.z,a3.w}*ww;
  }
  float* qb = q + ((size_t)b0*NH + h)*NE + e0 + e;
  #pragma unroll
  for (int j = 0; j < 8; ++j) {               // lanes e-consec: coalesced
    unsafeAtomicAdd(qb + (size_t)(2*j  )*NH*NE, acc2[j][0]);
    unsafeAtomicAdd(qb + (size_t)(2*j+1)*NH*NE, acc2[j][1]);
  }
}

// ---------------------------------------------------------------------------
// K2: stream enc once; energy -> exp (no max shift: |e| <~ 7; denom cancels
// in l2norm) -> ctx partial; block partials atomically summed into ctxacc.
__global__ __launch_bounds__(256, 4) void k_flash(
    const float* __restrict__ enc, const float* __restrict__ qg,
    float* __restrict__ ctxacc)
{
  const int s = blockIdx.x;
  const int b = blockIdx.y;
  const int t = threadIdx.x;
  const int wave = t >> 6;
  const int lane = t & 63;

  f2 qv[NH][4];
  const float* qb = qg + (size_t)b*NH*NE;
  #pragma unroll
  for (int h = 0; h < NH; ++h) {
    float4 a0 = *(const float4*)(qb + h*NE + 4*lane);
    float4 a1 = *(const float4*)(qb + h*NE + 256 + 4*lane);
    qv[h][0] = f2{a0.x, a0.y}; qv[h][1] = f2{a0.z, a0.w};
    qv[h][2] = f2{a1.x, a1.y}; qv[h][3] = f2{a1.z, a1.w};
  }
  f2 acc2[NH][4];
  #pragma unroll
  for (int h = 0; h < NH; ++h)
    #pragma unroll
    for (int j = 0; j < 4; ++j) acc2[h][j] = f2{0.f, 0.f};

  const int u0 = s*ROWS_PER_BLOCK + wave*ROWS_PER_WAVE;
  const float* encb = enc + ((size_t)b*NU + u0)*NE;
  #pragma unroll 2
  for (int r = 0; r < ROWS_PER_WAVE; ++r) {
    float4 v0 = *(const float4*)(encb + (size_t)r*NE + 4*lane);
    float4 v1 = *(const float4*)(encb + (size_t)r*NE + 256 + 4*lane);
    f2 e0 = f2{v0.x, v0.y}, e1 = f2{v0.z, v0.w};
    f2 e2 = f2{v1.x, v1.y}, e3 = f2{v1.z, v1.w};
    float d[NH];
    #pragma unroll
    for (int h = 0; h < NH; ++h) {
      f2 p = e0*qv[h][0] + e1*qv[h][1] + e2*qv[h][2] + e3*qv[h][3];
      d[h] = p[0] + p[1];
    }
    #pragma unroll
    for (int off = 1; off < 64; off <<= 1) {
      #pragma unroll
      for (int h = 0; h < NH; ++h) d[h] += __shfl_xor(d[h], off);
    }
    #pragma unroll
    for (int h = 0; h < NH; ++h) {
      float pf = __expf(d[h] * SCALE);
      f2 pp = f2{pf, pf};
      acc2[h][0] += pp*e0; acc2[h][1] += pp*e1;
      acc2[h][2] += pp*e2; acc2[h][3] += pp*e3;
    }
  }
  __shared__ float acc_lds[4][NH][NE];   // 32 KB
  #pragma unroll
  for (int h = 0; h < NH; ++h) {
    *(float4*)&acc_lds[wave][h][4*lane] =
        make_float4(acc2[h][0][0], acc2[h][0][1], acc2[h][1][0], acc2[h][1][1]);
    *(float4*)&acc_lds[wave][h][256 + 4*lane] =
        make_float4(acc2[h][2][0], acc2[h][2][1], acc2[h][3][0], acc2[h][3][1]);
  }
  __syncthreads();
  float* cb = ctxacc + (size_t)b*(NH*NE);
  #pragma unroll
  for (int h = 0; h < NH; ++h) {
    #pragma unroll
    for (int eo = 0; eo < 2; ++eo) {
      int e = t + eo*256;
      float v = acc_lds[0][h][e] + acc_lds[1][h][e] + acc_lds[2][h][e] + acc_lds[3][h][e];
      unsafeAtomicAdd(&cb[h*NE + e], v);
    }
  }
}

// ---------------------------------------------------------------------------
// K3: out += comb @ out_w chunk. Reads ctxacc, computes per-(b,h) l2-norm
// in-block (softmax denom cancels), split-K partials atomically added into
// bias-initialized out. grid (NA/256, NB/BT, RSPLIT).
__global__ __launch_bounds__(256) void k_out(
    const float* __restrict__ ctxacc, const float* __restrict__ out_w,
    float* __restrict__ out)
{
  const int t = threadIdx.x;
  const int a = blockIdx.x*256 + t;
  const int b0 = blockIdx.y * BT;
  const int rc = blockIdx.z;
  const int h  = rc >> 2;            // RCH=128 -> 4 chunks per head
  const int e0 = (rc & 3) * RCH;

  __shared__ float rn_lds[BT];
  const int wv = t >> 6, lane = t & 63;
  {
    const int i = 2*wv + (lane >> 5);
    const int l32 = lane & 31;
    const float* row = ctxacc + (size_t)(b0+i)*(NH*NE) + (size_t)h*NE;
    float ss = 0.f;
    #pragma unroll
    for (int j = 0; j < 16; ++j) { float v = row[l32 + 32*j]; ss += v*v; }
    #pragma unroll
    for (int off = 1; off < 32; off <<= 1) ss += __shfl_xor(ss, off);
    if (l32 == 0) rn_lds[i] = rsqrtf(fmaxf(ss, 1e-12f));
  }
  __syncthreads();

  __shared__ float c_lds[RCH][BT];   // 4 KB
  for (int g = t; g < RCH*BT; g += 256) {
    const int r = g & (RCH-1), i = g >> 7;
    c_lds[r][i] = ctxacc[(size_t)(b0+i)*(NH*NE) + (size_t)h*NE + e0 + r] * rn_lds[i];
  }
  __syncthreads();

  float accv[BT];
  #pragma unroll
  for (int i = 0; i < BT; ++i) accv[i] = 0.f;
  const float* w = out_w + ((size_t)rc*RCH)*NA + a;
  #pragma unroll 8
  for (int r = 0; r < RCH; ++r) {
    float wvv = w[(size_t)r*NA];
    float4 ca = *(const float4*)&c_lds[r][0];
    float4 cb = *(const float4*)&c_lds[r][4];
    accv[0] += ca.x*wvv; accv[1] += ca.y*wvv; accv[2] += ca.z*wvv; accv[3] += ca.w*wvv;
    accv[4] += cb.x*wvv; accv[5] += cb.y*wvv; accv[6] += cb.z*wvv; accv[7] += cb.w*wvv;
  }
  #pragma unroll
  for (int i = 0; i < BT; ++i)
    unsafeAtomicAdd(&out[(size_t)(b0+i)*NA + a], accv[i]);
}

// ---------------------------------------------------------------------------
extern "C" void kernel_launch(void* const* d_in, const int* in_sizes, int n_in,
                              void* d_out, int out_size, void* d_ws, size_t ws_size,
                              hipStream_t stream) {
  const float* dec   = (const float*)d_in[0];
  const float* enc   = (const float*)d_in[1];
  const float* phi_w = (const float*)d_in[2];
  const float* phi_b = (const float*)d_in[3];
  const float* psi_w = (const float*)d_in[4];
  // d_in[5] = psi_b: constant over u -> cancels in softmax.
  const float* out_w = (const float*)d_in[6];
  const float* out_b = (const float*)d_in[7];
  float* out = (float*)d_out;
  float* ws = (float*)d_ws;
  float* q      = ws + WS_Q;
  float* ctxacc = ws + WS_CTX;
  float* P      = ws + WS_P;

  hipLaunchKernelGGL(k_phi,   dim3(NH*4*DSP),              dim3(256), 0, stream,
                     dec, phi_w, P, q, ctxacc, out_b, out);
  hipLaunchKernelGGL(k_q,     dim3(128),                   dim3(256), 0, stream,
                     P, phi_b, psi_w, q);
  hipLaunchKernelGGL(k_flash, dim3(NS, NB),                dim3(256), 0, stream,
                     enc, q, ctxacc);
  hipLaunchKernelGGL(k_out,   dim3(NA/256, NB/BT, RSPLIT), dim3(256), 0, stream,
                     ctxacc, out_w, out);
}